// Round 18
// baseline (251.757 us; speedup 1.0000x reference)
//
#include <hip/hip_runtime.h>
#include <hip/hip_bf16.h>
#include <cstdint>
#include <cstddef>

#define H 512
#define NFEAT 1024
#define BATCH 16384
#define LM ((size_t)1 << 20)   // elems per 1024x1024 matrix
#define KOP 576                // padded K for the build GEMM (513 used)

using bf16 = __hip_bfloat16;
using bf16x8 = __attribute__((ext_vector_type(8))) __bf16;
using f32x4 = __attribute__((ext_vector_type(4))) float;
using f32x16 = __attribute__((ext_vector_type(16))) float;

// ---------------------------------------------------------------------------
// async global -> LDS, 16 bytes per lane
// ---------------------------------------------------------------------------
__device__ __forceinline__ void gload16(void* lds, const void* g) {
  __builtin_amdgcn_global_load_lds(
      (__attribute__((address_space(1))) void*)g,
      (__attribute__((address_space(3))) void*)lds,
      16, 0, 0);
}

// ---------------------------------------------------------------------------
// prepfused (R17-validated): Cayley closed form -> a[], b[] + prefix tables.
// ---------------------------------------------------------------------------
__global__ __launch_bounds__(256) void prepfused_kernel(
    const float* __restrict__ er, const float* __restrict__ ed,
    const float* __restrict__ dr, const float* __restrict__ dd,
    float* __restrict__ ab, float* __restrict__ Tpref) {
  __shared__ double sred[256], qred[256];
  __shared__ float sa[512];
  __shared__ float buf[4][512];
  __shared__ float tmp[4][512];

  const int mat = blockIdx.x;
  const int t = threadIdx.x;
  const float* u = (mat < 4) ? (er + mat * H) : (dr + (mat - 4) * H);
  const float* d = (mat < 4) ? (ed + mat * H) : (dd + (mat - 4) * H);

  {
    const double v0 = (double)u[t];
    const double v1 = (double)u[t + 256];
    sred[t] = v0 + v1;
    qred[t] = v0 * v0 + v1 * v1;
  }
  __syncthreads();
  for (int off = 128; off; off >>= 1) {
    if (t < off) {
      sred[t] += sred[t + off];
      qred[t] += qred[t + off];
    }
    __syncthreads();
  }
  const double s = sred[0];
  const double q = qred[0];
  const double det = 1.0 - s * s + (double)H * q;
  const double cuv = 2.0 * (1.0 + s) / det;
  const double cuu = -2.0 * (double)H / det;
  const double cvv = -2.0 * q / det;
  const double cvu = -2.0 * (1.0 - s) / det;

  float* a = ab + mat * 1024;
  float* b = a + H;
#pragma unroll
  for (int h = 0; h < 2; ++h) {
    const int idx = t + 256 * h;
    const double ui = (double)u[idx], di = (double)d[idx];
    const float av = (float)(di * (cuv * ui + cvv));
    const float bv = (float)(di * (cuu * ui + cvu));
    a[idx] = av;
    b[idx] = bv;
    sa[idx] = av;
  }
  __syncthreads();

  for (int m = t; m < 512; m += 256) {
    buf[0][m] = sa[m];
    buf[1][m] = sa[511 - m];
    buf[2][m] = d[m];
    buf[3][m] = d[511 - m];
  }
  __syncthreads();
  for (int st = 4; st <= 256; st <<= 1) {
    for (int m = t; m < 512; m += 256)
#pragma unroll
      for (int qq = 0; qq < 4; ++qq) tmp[qq][m] = (m >= st) ? buf[qq][m - st] : 0.f;
    __syncthreads();
    for (int m = t; m < 512; m += 256)
#pragma unroll
      for (int qq = 0; qq < 4; ++qq) buf[qq][m] += tmp[qq][m];
    __syncthreads();
  }
  float* tp = Tpref + mat * 2048;
  for (int m = t; m < 512; m += 256) {
    tp[m] = buf[0][m];
    tp[512 + m] = buf[1][m];
    tp[1024 + m] = buf[2][m];
    tp[1536 + m] = buf[3][m];
  }
}

// ---------------------------------------------------------------------------
// genops v3 (R17-validated): sea-GEMM operands + fused splith tail.
// ---------------------------------------------------------------------------
__global__ __launch_bounds__(256) void genops_kernel(
    const float* __restrict__ er, const float* __restrict__ dr,
    const float* __restrict__ ab,
    bf16* __restrict__ Ah, bf16* __restrict__ Bh, bf16* __restrict__ Bl,
    const float* __restrict__ x, bf16* __restrict__ Qh) {
  const int xr = blockIdx.x;           // 0..1023
  const int mat = blockIdx.y;          // 0..7
  const float* u = (mat < 4) ? (er + mat * H) : (dr + (mat - 4) * H);
  const float* b = ab + mat * 1024 + H;
  const int t = threadIdx.x;
  const size_t base = ((size_t)mat * 1024 + xr) * KOP;
  for (int k = t; k < KOP; k += 256) {
    float av = 0.f, bv = 0.f;
    if (k <= 128) {
      const int o = 4 * k;
      const int ia = xr - o;
      av = (ia >= 0 && ia < 512) ? b[ia] : 0.f;
      bv = (ia >= 0 && ia < 512) ? u[ia] : 0.f;
    } else if (k <= 256) {
      const int o = 4 * (k - 129) + 1;
      const int ia = 511 - xr + o;
      const int ib = xr - o;
      av = (ia >= 0 && ia < 512) ? u[ia] : 0.f;
      bv = (ib >= 0 && ib < 512) ? b[ib] : 0.f;
    } else if (k <= 384) {
      const int o = 4 * (k - 257) + 2;
      const int ia = 511 - xr + o;
      av = (ia >= 0 && ia < 512) ? b[ia] : 0.f;
      bv = (ia >= 0 && ia < 512) ? u[ia] : 0.f;
    } else if (k <= 512) {
      const int o = 4 * (k - 385) + 3;
      const int ia = xr - o;
      const int ib = 511 - xr + o;
      av = (ia >= 0 && ia < 512) ? u[ia] : 0.f;
      bv = (ib >= 0 && ib < 512) ? b[ib] : 0.f;
    }
    Ah[base + k] = __float2bfloat16(av);
    const bf16 bh = __float2bfloat16(bv);
    Bh[base + k] = bh;
    Bl[base + k] = __float2bfloat16(bv - __bfloat162float(bh));
  }

  const int n4 = BATCH * NFEAT / 4;
  const int gidx = (mat * 1024 + xr) * 256 + t;
  for (int i = gidx; i < n4; i += 8192 * 256) {
    float4 v = ((const float4*)x)[i];
    union { bf16 bb[4]; short4 sv; } Hu;
    Hu.bb[0] = __float2bfloat16(v.x);
    Hu.bb[1] = __float2bfloat16(v.y);
    Hu.bb[2] = __float2bfloat16(v.z);
    Hu.bb[3] = __float2bfloat16(v.w);
    ((short4*)Qh)[i] = Hu.sv;
  }
}

// ---------------------------------------------------------------------------
// buildgemm v2 (R16/R17-validated): L[mat] = Aop @ Bop^T (2-pass) with
// a-part / diagonal terms fused in the epilogue.  128x128 tile, BK=64.
// ---------------------------------------------------------------------------
__global__ __launch_bounds__(256) void buildgemm_kernel(
    const bf16* __restrict__ Ah, const bf16* __restrict__ Bh,
    const bf16* __restrict__ Bl,
    const float* __restrict__ ed, const float* __restrict__ dd,
    const float* __restrict__ Tpref, bf16* __restrict__ Lbase) {
  __shared__ __align__(16) bf16 smem[3 * 8192];
  __shared__ float pa[512], parev[512], pd[512], pdrev[512], sdl[512];
  bf16* sAh = smem;
  bf16* sBh = smem + 8192;
  bf16* sBl = smem + 16384;

  const int tid = threadIdx.x;
  const int lane = tid & 63;
  const int wave = tid >> 6;
  const int wr = wave >> 1;
  const int wc = wave & 1;
  const int mat = blockIdx.z;
  const int row0 = blockIdx.x * 128;
  const int col0 = blockIdx.y * 128;

  {
    const float* tp = Tpref + mat * 2048;
    const float* d = (mat < 4) ? (ed + mat * H) : (dd + (mat - 4) * H);
    for (int m = tid; m < 512; m += 256) {
      pa[m] = tp[m];
      parev[m] = tp[512 + m];
      pd[m] = tp[1024 + m];
      pdrev[m] = tp[1536 + m];
      sdl[m] = d[m];
    }
  }

  const size_t OPS = (size_t)mat * 1024 * KOP;
  const int srow = tid >> 3;
  const int sce = (((tid * 16) ^ (((tid >> 3) & 7) << 4)) & 127) >> 1;
  const size_t abase = OPS + (size_t)(row0 + srow) * KOP + sce;
  const size_t bbase = OPS + (size_t)(col0 + srow) * KOP + sce;
  const int dst0 = tid * 8;

  f32x16 acc[2][2] = {};

  for (int kt = 0; kt < 9; ++kt) {
    const int k0 = kt * 64;
#pragma unroll
    for (int q = 0; q < 4; ++q) {
      const size_t ga = abase + (size_t)(32 * q) * KOP + k0;
      const size_t gb = bbase + (size_t)(32 * q) * KOP + k0;
      const int dq = q * 2048 + dst0;
      gload16(sAh + dq, Ah + ga);
      gload16(sBh + dq, Bh + gb);
      gload16(sBl + dq, Bl + gb);
    }
    __syncthreads();

    const int l31 = lane & 31;
    const int kh16 = (lane >> 5) * 16;
#pragma unroll
    for (int ks = 0; ks < 4; ++ks) {
      bf16x8 fah[2], fbh[2], fbl[2];
#pragma unroll
      for (int m = 0; m < 2; ++m) {
        const int arow = wr * 64 + m * 32 + l31;
        const int abk = (arow * 128 + ks * 32 + kh16) ^ ((arow & 7) << 4);
        fah[m] = *(const bf16x8*)((const char*)sAh + abk);
        const int brow = wc * 64 + m * 32 + l31;
        const int bbk = (brow * 128 + ks * 32 + kh16) ^ ((brow & 7) << 4);
        fbh[m] = *(const bf16x8*)((const char*)sBh + bbk);
        fbl[m] = *(const bf16x8*)((const char*)sBl + bbk);
      }
#pragma unroll
      for (int m = 0; m < 2; ++m)
#pragma unroll
        for (int n = 0; n < 2; ++n) {
          acc[m][n] = __builtin_amdgcn_mfma_f32_32x32x16_bf16(fah[m], fbh[n], acc[m][n], 0, 0, 0);
          acc[m][n] = __builtin_amdgcn_mfma_f32_32x32x16_bf16(fah[m], fbl[n], acc[m][n], 0, 0, 0);
        }
    }
    __syncthreads();
  }

  auto apart = [&](int i, int j) -> float {
    const int lo = max(0, max(i, j) - 511);
    const int hi = min(512, min(i, j));
    if (lo > hi) return 0.f;
    float v = 0.f;
    {
      int o1 = lo + ((0 - lo) & 3), o2 = hi - (hi & 3);
      if (o1 <= o2) { int mx = i - o1, mn = i - o2; v += pa[mx] - (mn >= 4 ? pa[mn - 4] : 0.f); }
    }
    {
      int o1 = lo + ((1 - lo) & 3), o2 = hi - ((hi - 1) & 3);
      if (o1 <= o2) { int mx = j - o1, mn = j - o2; v += pa[mx] - (mn >= 4 ? pa[mn - 4] : 0.f); }
    }
    {
      int o1 = lo + ((2 - lo) & 3), o2 = hi - ((hi - 2) & 3);
      if (o1 <= o2) { int mx = i - o1, mn = i - o2; v += parev[mx] - (mn >= 4 ? parev[mn - 4] : 0.f); }
    }
    {
      int o1 = lo + ((3 - lo) & 3), o2 = hi - ((hi - 3) & 3);
      if (o1 <= o2) { int mx = j - o1, mn = j - o2; v += parev[mx] - (mn >= 4 ? parev[mn - 4] : 0.f); }
    }
    if (i == j) {
      {
        int o1 = lo + ((0 - lo) & 3), o2 = hi - (hi & 3);
        if (o1 <= o2) { int mx = i - o1, mn = i - o2; v += pd[mx] - (mn >= 4 ? pd[mn - 4] : 0.f); }
      }
      {
        int o1 = lo + ((2 - lo) & 3), o2 = hi - ((hi - 2) & 3);
        if (o1 <= o2) { int mx = i - o1, mn = i - o2; v += pdrev[mx] - (mn >= 4 ? pdrev[mn - 4] : 0.f); }
      }
    }
    const int m2 = i + j - 511;
    if (m2 >= 0 && !(m2 & 1)) {
      const int os = m2 >> 1;
      if (os >= lo && os <= hi) {
        const int r = os & 3;
        if (r == 1) v += sdl[j - os];
        else if (r == 3) v += sdl[511 - (j - os)];
      }
    }
    return v;
  };

  const int ocol0 = col0 + wc * 64 + (lane & 31);
  const int rb = (lane >> 5) << 2;
#pragma unroll
  for (int m = 0; m < 2; ++m)
#pragma unroll
    for (int n = 0; n < 2; ++n)
#pragma unroll
      for (int r = 0; r < 16; ++r) {
        const int grow = row0 + wr * 64 + m * 32 + (r & 3) + ((r >> 2) << 3) + rb;
        const int gcol = ocol0 + n * 32;
        const float v = acc[m][n][r] + apart(grow, gcol);
        const size_t off = ((size_t)mat << 21) + ((size_t)grow << 10) + (size_t)gcol;
        const bf16 hb = __float2bfloat16(v);
        Lbase[off] = hb;
        Lbase[off + LM] = __float2bfloat16(v - __bfloat162float(hb));
      }
}

// ---------------------------------------------------------------------------
// batched single-array transpose: D = S^T for one 1024x1024 bf16 array per z.
// ---------------------------------------------------------------------------
struct TPtrs { const bf16* s; bf16* d; };
struct T6 { TPtrs t[6]; };

__global__ __launch_bounds__(256) void transposeB_kernel(T6 p) {
  const bf16* S = p.t[blockIdx.z].s;
  bf16* D = p.t[blockIdx.z].d;
  __shared__ ushort tile[64][68];
  const int i0 = blockIdx.x * 64, j0 = blockIdx.y * 64;
  const int tid = threadIdx.x;
  const int rr = tid >> 4;
  const int cc = (tid & 15) * 4;
#pragma unroll
  for (int it = 0; it < 4; ++it) {
    const int row = it * 16 + rr;
    const size_t so = (size_t)(i0 + row) * 1024 + j0 + cc;
    ushort4 v = *(const ushort4*)((const ushort*)S + so);
    tile[row][cc] = v.x; tile[row][cc + 1] = v.y;
    tile[row][cc + 2] = v.z; tile[row][cc + 3] = v.w;
  }
  __syncthreads();
#pragma unroll
  for (int it = 0; it < 4; ++it) {
    const int row = it * 16 + rr;
    ushort4 o;
    o.x = tile[cc][row];     o.y = tile[cc + 1][row];
    o.z = tile[cc + 2][row]; o.w = tile[cc + 3][row];
    const size_t dofs = (size_t)(j0 + row) * 1024 + i0 + cc;
    *(ushort4*)((ushort*)D + dofs) = o;
  }
}

// ---------------------------------------------------------------------------
// chaingemm5: 2-pass chain GEMM on the gemmbig-v4 skeleton.
// Y = A * B^T per z.  A single-bf16; B pair (lo at b+LM).  Output split.
// 128x128 tile, 4 waves (2x2 of 64x64), BK=32, mfma_f32_16x16x32_bf16,
// ring-3 LDS (3 x (A 8KB + Bh 8KB + Bl 8KB) = 72 KiB) -> 2 blocks/CU,
// 6 loads/tile, stage T+2, counted vmcnt(6), 1 barrier/tile (same constants
// as the R15/R16/R17-validated gemmbig v4).
// ---------------------------------------------------------------------------
struct GPtrs { const bf16* a; const bf16* b; bf16* yh; bf16* yl; };
struct G4 { GPtrs g[4]; };

__global__ __launch_bounds__(256, 2) void chaingemm5_kernel(G4 p) {
  GPtrs q = p.g[blockIdx.z];
  const bf16* A = q.a;
  const bf16* Bh = q.b;
  const bf16* Bl = q.b + LM;

  __shared__ __align__(16) bf16 smem[3 * 12288];  // 72 KiB

  const int tid = threadIdx.x;
  const int lane = tid & 63;
  const int wave = tid >> 6;     // 0..3
  const int wr = wave >> 1;      // 0..1 : 64-row half
  const int wc = wave & 1;       // 0..1 : 64-col half
  const int r0 = blockIdx.x * 128, c0 = blockIdx.y * 128;

  // staging (gemmbig-v4 pattern): dest linear tid*16B; source col pre-swizzled
  const int sr = tid >> 2;                            // 0..63
  const int sc = ((tid & 3) ^ ((tid >> 3) & 3)) * 8;  // src col elem
  const size_t abase0 = (size_t)(r0 + sr) * 1024 + sc;
  const size_t abase1 = abase0 + (size_t)64 * 1024;
  const size_t bbase0 = (size_t)(c0 + sr) * 1024 + sc;
  const size_t bbase1 = bbase0 + (size_t)64 * 1024;
  const int dst = tid * 8;

  auto STAGE = [&](int buf, int k0) {   // 6 gload16 per tile
    bf16* base = smem + buf * 12288;
    gload16(base + dst, A + abase0 + k0);
    gload16(base + 2048 + dst, A + abase1 + k0);
    gload16(base + 4096 + dst, Bh + bbase0 + k0);
    gload16(base + 4096 + 2048 + dst, Bh + bbase1 + k0);
    gload16(base + 8192 + dst, Bl + bbase0 + k0);
    gload16(base + 8192 + 2048 + dst, Bl + bbase1 + k0);
  };

  // frag-read byte offsets (gemmbig-v4 swizzle: key = row bits 1-2)
  const int l15 = lane & 15;
  const int kcol = ((lane >> 4) * 16) ^ (((l15 >> 1) & 3) << 4);
  int aoff[4], bhoff[4], bloff[4];
#pragma unroll
  for (int fr = 0; fr < 4; ++fr) {
    const int arow = wr * 64 + fr * 16 + l15;
    aoff[fr] = arow * 64 + kcol;
    const int brow = wc * 64 + fr * 16 + l15;
    bhoff[fr] = 8192 + brow * 64 + kcol;
    bloff[fr] = 16384 + brow * 64 + kcol;
  }

  auto LD = [&](int buf, int off) {
    return *(const bf16x8*)((const char*)(smem + buf * 12288) + off);
  };

  f32x4 acc[4][4] = {};

  STAGE(0, 0);
  STAGE(1, 32);
  asm volatile("s_waitcnt vmcnt(6)" ::: "memory");
  __builtin_amdgcn_s_barrier();

  for (int T = 0; T < 32; ++T) {
    const int buf = T % 3;
    if (T < 30) STAGE((T + 2) % 3, (T + 2) * 32);

    bf16x8 fa[4], fbh[4], fbl[4];
#pragma unroll
    for (int fr = 0; fr < 4; ++fr) fa[fr] = LD(buf, aoff[fr]);
#pragma unroll
    for (int fc = 0; fc < 4; ++fc) {
      fbh[fc] = LD(buf, bhoff[fc]);
      fbl[fc] = LD(buf, bloff[fc]);
    }
    __builtin_amdgcn_s_setprio(1);
#pragma unroll
    for (int fr = 0; fr < 4; ++fr)
#pragma unroll
      for (int fc = 0; fc < 4; ++fc) {
        acc[fr][fc] = __builtin_amdgcn_mfma_f32_16x16x32_bf16(fa[fr], fbh[fc], acc[fr][fc], 0, 0, 0);
        acc[fr][fc] = __builtin_amdgcn_mfma_f32_16x16x32_bf16(fa[fr], fbl[fc], acc[fr][fc], 0, 0, 0);
      }
    __builtin_amdgcn_s_setprio(0);

    if (T <= 29) {
      asm volatile("s_waitcnt vmcnt(6)" ::: "memory");
    } else if (T == 30) {
      asm volatile("s_waitcnt vmcnt(0)" ::: "memory");
    }
    __builtin_amdgcn_s_barrier();
  }

  // epilogue: 16x16 C/D layout: col = lane&15, row = (lane>>4)*4 + reg
  const int orow = r0 + wr * 64 + (lane >> 4) * 4;
  const int ocol = c0 + wc * 64 + l15;
#pragma unroll
  for (int fr = 0; fr < 4; ++fr)
#pragma unroll
    for (int fc = 0; fc < 4; ++fc)
#pragma unroll
      for (int r = 0; r < 4; ++r) {
        const int gr = orow + fr * 16 + r;
        const int gc = ocol + fc * 16;
        const size_t off = (size_t)gr * 1024 + gc;
        const float v = acc[fr][fc][r];
        const bf16 hb = __float2bfloat16(v);
        q.yh[off] = hb;
        q.yl[off] = __float2bfloat16(v - __bfloat162float(hb));
      }
}

// ---------------------------------------------------------------------------
// fused SINGLE-PASS big GEMM v4 (R15/R16/R17-validated, unchanged):
//   Y[r][c] = sum_k xh[r][k] * Mcat_h[c][k];  c<1024 -> O0, else O1.
// ---------------------------------------------------------------------------
__global__ __launch_bounds__(256, 2) void gemmbig_kernel(
    const bf16* __restrict__ A, const bf16* __restrict__ Bh_,
    float* __restrict__ Y0, float* __restrict__ Y1) {
  __shared__ __align__(16) bf16 smem[3 * 12288];  // 72 KiB

  const int tid = threadIdx.x;
  const int lane = tid & 63;
  const int wave = tid >> 6;
  const int wr = wave >> 1;
  const int wc = wave & 1;

  const int pdisp = blockIdx.x;
  const int xcd = pdisp & 7;
  const int chk = pdisp >> 3;
  const int row0 = (xcd * 16 + (chk >> 3)) * 128;
  const int col0 = (chk & 7) * 256;

  const int sr = tid >> 2;
  const int sc = ((tid & 3) ^ ((tid >> 3) & 3)) * 8;
  const size_t abase0 = (size_t)(row0 + sr) * NFEAT + sc;
  const size_t abase1 = abase0 + (size_t)64 * NFEAT;
  const size_t bbase = (size_t)(col0 + sr) * NFEAT + sc;
  const int dst = tid * 8;

  auto STAGE_A = [&](int buf, int k0) {
    bf16* base = smem + buf * 12288;
    gload16(base + dst, A + abase0 + k0);
    gload16(base + 2048 + dst, A + abase1 + k0);
  };
  auto STAGE_B = [&](int buf, int k0) {
    bf16* base = smem + buf * 12288 + 4096;
#pragma unroll
    for (int q = 0; q < 4; ++q)
      gload16(base + q * 2048 + dst, Bh_ + bbase + (size_t)(64 * q) * NFEAT + k0);
  };

  const int l15 = lane & 15;
  const int kcol = ((lane >> 4) * 16) ^ (((l15 >> 1) & 3) << 4);
  int aoff[4], boff[8];
#pragma unroll
  for (int fr = 0; fr < 4; ++fr)
    aoff[fr] = (wr * 64 + fr * 16 + l15) * 64 + kcol;
#pragma unroll
  for (int fc = 0; fc < 8; ++fc)
    boff[fc] = 8192 + (wc * 128 + fc * 16 + l15) * 64 + kcol;

  auto LD = [&](int buf, int off) {
    return *(const bf16x8*)((const char*)(smem + buf * 12288) + off);
  };

  f32x4 acc[4][8] = {};

  STAGE_A(0, 0); STAGE_B(0, 0);
  STAGE_A(1, 32); STAGE_B(1, 32);
  asm volatile("s_waitcnt vmcnt(6)" ::: "memory");
  __builtin_amdgcn_s_barrier();

  for (int T = 0; T < 32; ++T) {
    const int buf = T % 3;
    if (T < 30) {
      const int nb = (T + 2) % 3;
      STAGE_A(nb, (T + 2) * 32);
      STAGE_B(nb, (T + 2) * 32);
    }

    bf16x8 fa[4], fb[4];
#pragma unroll
    for (int fr = 0; fr < 4; ++fr) fa[fr] = LD(buf, aoff[fr]);
#pragma unroll
    for (int fc = 0; fc < 4; ++fc) fb[fc] = LD(buf, boff[fc]);
    __builtin_amdgcn_s_setprio(1);
#pragma unroll
    for (int fr = 0; fr < 4; ++fr)
#pragma unroll
      for (int fc = 0; fc < 4; ++fc)
        acc[fr][fc] = __builtin_amdgcn_mfma_f32_16x16x32_bf16(fa[fr], fb[fc], acc[fr][fc], 0, 0, 0);
    __builtin_amdgcn_s_setprio(0);
#pragma unroll
    for (int fc = 0; fc < 4; ++fc) fb[fc] = LD(buf, boff[4 + fc]);
    __builtin_amdgcn_s_setprio(1);
#pragma unroll
    for (int fr = 0; fr < 4; ++fr)
#pragma unroll
      for (int fc = 0; fc < 4; ++fc)
        acc[fr][4 + fc] = __builtin_amdgcn_mfma_f32_16x16x32_bf16(fa[fr], fb[fc], acc[fr][4 + fc], 0, 0, 0);
    __builtin_amdgcn_s_setprio(0);

    if (T <= 29) {
      asm volatile("s_waitcnt vmcnt(6)" ::: "memory");
    } else if (T == 30) {
      asm volatile("s_waitcnt vmcnt(0)" ::: "memory");
    }
    __builtin_amdgcn_s_barrier();
  }

  float* Yb = (col0 < 1024) ? Y0 : (Y1 - 1024);
  const int orow = row0 + wr * 64 + (lane >> 4) * 4;
  const int ocol = col0 + wc * 128 + l15;
#pragma unroll
  for (int fr = 0; fr < 4; ++fr)
#pragma unroll
    for (int fc = 0; fc < 8; ++fc)
#pragma unroll
      for (int r = 0; r < 4; ++r) {
        const int grow = orow + fr * 16 + r;
        const int gcol = ocol + fc * 16;
        Yb[(size_t)grow * NFEAT + (size_t)gcol] = acc[fr][fc][r];
      }
}

// ---------------------------------------------------------------------------
// launch
// ---------------------------------------------------------------------------
extern "C" void kernel_launch(void* const* d_in, const int* in_sizes, int n_in,
                              void* d_out, int out_size, void* d_ws, size_t ws_size,
                              hipStream_t stream) {
  (void)in_sizes; (void)n_in; (void)out_size; (void)ws_size;
  const float* x  = (const float*)d_in[0];
  const float* er = (const float*)d_in[1];
  const float* ed = (const float*)d_in[2];
  const float* dr = (const float*)d_in[3];
  const float* dd = (const float*)d_in[4];

  float* O0 = (float*)d_out;                       // bottleneck (fp32, 64 MB)
  float* O1 = O0 + (size_t)BATCH * NFEAT;          // out (fp32, 64 MB)

  // d_ws: L pairs [16 LM] (32MB) | ab (32KB) | Qh (32MB)
  bf16* Lb = (bf16*)d_ws;
  float* ab = (float*)(Lb + 16 * LM);
  bf16* Qh = (bf16*)(ab + 8 * 1024);

  // O0 scratch: Tpref @0 (64KB); 16 chain slots @1MB.
  float* Tpref = O0;
  bf16* SB = (bf16*)((char*)O0 + (1 << 20));
  auto slot = [&](int s) { return SB + (size_t)s * LM; };

  // O1 scratch (dead until gemmbig): sea-GEMM operands, 3 x 9.44MB.
  const size_t OPN = (size_t)8 * 1024 * KOP;
  bf16* Aoph = (bf16*)O1;
  bf16* Boph = Aoph + OPN;
  bf16* Bopl = Boph + OPN;

  prepfused_kernel<<<8, 256, 0, stream>>>(er, ed, dr, dd, ab, Tpref);
  genops_kernel<<<dim3(1024, 8), 256, 0, stream>>>(er, dr, ab, Aoph, Boph, Bopl, x, Qh);
  buildgemm_kernel<<<dim3(8, 8, 8), 256, 0, stream>>>(Aoph, Boph, Bopl,
                                                      ed, dd, Tpref, Lb);

  // ---- tree fold ----
  {
    T6 p;
    p.t[0] = {Lb + 0 * LM,  slot(0)};   // L1h -> s0  (T1e hi)
    p.t[1] = {Lb + 4 * LM,  slot(2)};   // L3h -> s2  (T2e hi)
    p.t[2] = {Lb + 5 * LM,  slot(3)};   // L3l -> s3  (T2e lo)
    p.t[3] = {Lb + 8 * LM,  slot(4)};   // L5h -> s4  (T1d hi)
    p.t[4] = {Lb + 12 * LM, slot(6)};   // L7h -> s6  (T2d hi)
    p.t[5] = {Lb + 13 * LM, slot(7)};   // L7l -> s7  (T2d lo)
    transposeB_kernel<<<dim3(16, 16, 6), 256, 0, stream>>>(p);
  }
  {
    G4 p;
    p.g[0] = {slot(0),      Lb + 2 * LM,  slot(8),  slot(9)};   // Q1e = T1e * L2^T
    p.g[1] = {Lb + 6 * LM,  slot(2),      slot(10), slot(11)};  // Q2te = L4 * T2e^T
    p.g[2] = {slot(4),      Lb + 10 * LM, slot(12), slot(13)};  // Q1d = T1d * L6^T
    p.g[3] = {Lb + 14 * LM, slot(6),      slot(14), slot(15)};  // Q2td = L8 * T2d^T
    chaingemm5_kernel<<<dim3(8, 8, 4), 256, 0, stream>>>(p);
  }
  {
    G4 p;
    p.g[0] = {slot(8),  slot(10), slot(0), slot(1)};   // Kce = Menc^T
    p.g[1] = {slot(12), slot(14), slot(2), slot(3)};   // Kcd = Mdec^T
    p.g[2] = p.g[0];
    p.g[3] = p.g[1];
    chaingemm5_kernel<<<dim3(8, 8, 2), 256, 0, stream>>>(p);
  }
  {
    T6 p;
    p.t[0] = {slot(0), Lb + 0 * LM};    // Menc -> Mcat rows 0-1023
    p.t[1] = {slot(2), Lb + 2 * LM};    // Mdec
    p.t[2] = p.t[0]; p.t[3] = p.t[0]; p.t[4] = p.t[0]; p.t[5] = p.t[0];
    transposeB_kernel<<<dim3(16, 16, 2), 256, 0, stream>>>(p);
  }
  {
    G4 p;
    p.g[0] = {Lb + 2 * LM, slot(0), Lb + 1 * LM, slot(4)};  // Mtot -> Mcat rows 1024+
    p.g[1] = p.g[0]; p.g[2] = p.g[0]; p.g[3] = p.g[0];
    chaingemm5_kernel<<<dim3(8, 8, 1), 256, 0, stream>>>(p);
  }

  // fused single-pass big GEMM: both outputs from x in one dispatch.
  gemmbig_kernel<<<1024, 256, 0, stream>>>(Qh, Lb, O0, O1);
}

// Round 19
// 238.914 us; speedup vs baseline: 1.0538x; 1.0538x over previous
//
#include <hip/hip_runtime.h>
#include <hip/hip_bf16.h>
#include <cstdint>
#include <cstddef>

#define H 512
#define NFEAT 1024
#define BATCH 16384
#define LM ((size_t)1 << 20)   // elems per 1024x1024 matrix
#define KOP 576                // padded K for the build GEMM (513 used)

using bf16 = __hip_bfloat16;
using bf16x8 = __attribute__((ext_vector_type(8))) __bf16;
using f32x4 = __attribute__((ext_vector_type(4))) float;
using f32x16 = __attribute__((ext_vector_type(16))) float;

// ---------------------------------------------------------------------------
// async global -> LDS, 16 bytes per lane
// ---------------------------------------------------------------------------
__device__ __forceinline__ void gload16(void* lds, const void* g) {
  __builtin_amdgcn_global_load_lds(
      (__attribute__((address_space(1))) void*)g,
      (__attribute__((address_space(3))) void*)lds,
      16, 0, 0);
}

// ---------------------------------------------------------------------------
// prepfused (R17-validated): Cayley closed form -> a[], b[] + prefix tables.
// ---------------------------------------------------------------------------
__global__ __launch_bounds__(256) void prepfused_kernel(
    const float* __restrict__ er, const float* __restrict__ ed,
    const float* __restrict__ dr, const float* __restrict__ dd,
    float* __restrict__ ab, float* __restrict__ Tpref) {
  __shared__ double sred[256], qred[256];
  __shared__ float sa[512];
  __shared__ float buf[4][512];
  __shared__ float tmp[4][512];

  const int mat = blockIdx.x;
  const int t = threadIdx.x;
  const float* u = (mat < 4) ? (er + mat * H) : (dr + (mat - 4) * H);
  const float* d = (mat < 4) ? (ed + mat * H) : (dd + (mat - 4) * H);

  {
    const double v0 = (double)u[t];
    const double v1 = (double)u[t + 256];
    sred[t] = v0 + v1;
    qred[t] = v0 * v0 + v1 * v1;
  }
  __syncthreads();
  for (int off = 128; off; off >>= 1) {
    if (t < off) {
      sred[t] += sred[t + off];
      qred[t] += qred[t + off];
    }
    __syncthreads();
  }
  const double s = sred[0];
  const double q = qred[0];
  const double det = 1.0 - s * s + (double)H * q;
  const double cuv = 2.0 * (1.0 + s) / det;
  const double cuu = -2.0 * (double)H / det;
  const double cvv = -2.0 * q / det;
  const double cvu = -2.0 * (1.0 - s) / det;

  float* a = ab + mat * 1024;
  float* b = a + H;
#pragma unroll
  for (int h = 0; h < 2; ++h) {
    const int idx = t + 256 * h;
    const double ui = (double)u[idx], di = (double)d[idx];
    const float av = (float)(di * (cuv * ui + cvv));
    const float bv = (float)(di * (cuu * ui + cvu));
    a[idx] = av;
    b[idx] = bv;
    sa[idx] = av;
  }
  __syncthreads();

  for (int m = t; m < 512; m += 256) {
    buf[0][m] = sa[m];
    buf[1][m] = sa[511 - m];
    buf[2][m] = d[m];
    buf[3][m] = d[511 - m];
  }
  __syncthreads();
  for (int st = 4; st <= 256; st <<= 1) {
    for (int m = t; m < 512; m += 256)
#pragma unroll
      for (int qq = 0; qq < 4; ++qq) tmp[qq][m] = (m >= st) ? buf[qq][m - st] : 0.f;
    __syncthreads();
    for (int m = t; m < 512; m += 256)
#pragma unroll
      for (int qq = 0; qq < 4; ++qq) buf[qq][m] += tmp[qq][m];
    __syncthreads();
  }
  float* tp = Tpref + mat * 2048;
  for (int m = t; m < 512; m += 256) {
    tp[m] = buf[0][m];
    tp[512 + m] = buf[1][m];
    tp[1024 + m] = buf[2][m];
    tp[1536 + m] = buf[3][m];
  }
}

// ---------------------------------------------------------------------------
// genops v3 (R17-validated): sea-GEMM operands + fused splith tail.
// ---------------------------------------------------------------------------
__global__ __launch_bounds__(256) void genops_kernel(
    const float* __restrict__ er, const float* __restrict__ dr,
    const float* __restrict__ ab,
    bf16* __restrict__ Ah, bf16* __restrict__ Bh, bf16* __restrict__ Bl,
    const float* __restrict__ x, bf16* __restrict__ Qh) {
  const int xr = blockIdx.x;           // 0..1023
  const int mat = blockIdx.y;          // 0..7
  const float* u = (mat < 4) ? (er + mat * H) : (dr + (mat - 4) * H);
  const float* b = ab + mat * 1024 + H;
  const int t = threadIdx.x;
  const size_t base = ((size_t)mat * 1024 + xr) * KOP;
  for (int k = t; k < KOP; k += 256) {
    float av = 0.f, bv = 0.f;
    if (k <= 128) {
      const int o = 4 * k;
      const int ia = xr - o;
      av = (ia >= 0 && ia < 512) ? b[ia] : 0.f;
      bv = (ia >= 0 && ia < 512) ? u[ia] : 0.f;
    } else if (k <= 256) {
      const int o = 4 * (k - 129) + 1;
      const int ia = 511 - xr + o;
      const int ib = xr - o;
      av = (ia >= 0 && ia < 512) ? u[ia] : 0.f;
      bv = (ib >= 0 && ib < 512) ? b[ib] : 0.f;
    } else if (k <= 384) {
      const int o = 4 * (k - 257) + 2;
      const int ia = 511 - xr + o;
      av = (ia >= 0 && ia < 512) ? b[ia] : 0.f;
      bv = (ia >= 0 && ia < 512) ? u[ia] : 0.f;
    } else if (k <= 512) {
      const int o = 4 * (k - 385) + 3;
      const int ia = xr - o;
      const int ib = 511 - xr + o;
      av = (ia >= 0 && ia < 512) ? u[ia] : 0.f;
      bv = (ib >= 0 && ib < 512) ? b[ib] : 0.f;
    }
    Ah[base + k] = __float2bfloat16(av);
    const bf16 bh = __float2bfloat16(bv);
    Bh[base + k] = bh;
    Bl[base + k] = __float2bfloat16(bv - __bfloat162float(bh));
  }

  const int n4 = BATCH * NFEAT / 4;
  const int gidx = (mat * 1024 + xr) * 256 + t;
  for (int i = gidx; i < n4; i += 8192 * 256) {
    float4 v = ((const float4*)x)[i];
    union { bf16 bb[4]; short4 sv; } Hu;
    Hu.bb[0] = __float2bfloat16(v.x);
    Hu.bb[1] = __float2bfloat16(v.y);
    Hu.bb[2] = __float2bfloat16(v.z);
    Hu.bb[3] = __float2bfloat16(v.w);
    ((short4*)Qh)[i] = Hu.sv;
  }
}

// ---------------------------------------------------------------------------
// buildgemm v2 (R16/R17-validated): L[mat] = Aop @ Bop^T (2-pass) with
// a-part / diagonal terms fused in the epilogue.  128x128 tile, BK=64.
// ---------------------------------------------------------------------------
__global__ __launch_bounds__(256) void buildgemm_kernel(
    const bf16* __restrict__ Ah, const bf16* __restrict__ Bh,
    const bf16* __restrict__ Bl,
    const float* __restrict__ ed, const float* __restrict__ dd,
    const float* __restrict__ Tpref, bf16* __restrict__ Lbase) {
  __shared__ __align__(16) bf16 smem[3 * 8192];
  __shared__ float pa[512], parev[512], pd[512], pdrev[512], sdl[512];
  bf16* sAh = smem;
  bf16* sBh = smem + 8192;
  bf16* sBl = smem + 16384;

  const int tid = threadIdx.x;
  const int lane = tid & 63;
  const int wave = tid >> 6;
  const int wr = wave >> 1;
  const int wc = wave & 1;
  const int mat = blockIdx.z;
  const int row0 = blockIdx.x * 128;
  const int col0 = blockIdx.y * 128;

  {
    const float* tp = Tpref + mat * 2048;
    const float* d = (mat < 4) ? (ed + mat * H) : (dd + (mat - 4) * H);
    for (int m = tid; m < 512; m += 256) {
      pa[m] = tp[m];
      parev[m] = tp[512 + m];
      pd[m] = tp[1024 + m];
      pdrev[m] = tp[1536 + m];
      sdl[m] = d[m];
    }
  }

  const size_t OPS = (size_t)mat * 1024 * KOP;
  const int srow = tid >> 3;
  const int sce = (((tid * 16) ^ (((tid >> 3) & 7) << 4)) & 127) >> 1;
  const size_t abase = OPS + (size_t)(row0 + srow) * KOP + sce;
  const size_t bbase = OPS + (size_t)(col0 + srow) * KOP + sce;
  const int dst0 = tid * 8;

  f32x16 acc[2][2] = {};

  for (int kt = 0; kt < 9; ++kt) {
    const int k0 = kt * 64;
#pragma unroll
    for (int q = 0; q < 4; ++q) {
      const size_t ga = abase + (size_t)(32 * q) * KOP + k0;
      const size_t gb = bbase + (size_t)(32 * q) * KOP + k0;
      const int dq = q * 2048 + dst0;
      gload16(sAh + dq, Ah + ga);
      gload16(sBh + dq, Bh + gb);
      gload16(sBl + dq, Bl + gb);
    }
    __syncthreads();

    const int l31 = lane & 31;
    const int kh16 = (lane >> 5) * 16;
#pragma unroll
    for (int ks = 0; ks < 4; ++ks) {
      bf16x8 fah[2], fbh[2], fbl[2];
#pragma unroll
      for (int m = 0; m < 2; ++m) {
        const int arow = wr * 64 + m * 32 + l31;
        const int abk = (arow * 128 + ks * 32 + kh16) ^ ((arow & 7) << 4);
        fah[m] = *(const bf16x8*)((const char*)sAh + abk);
        const int brow = wc * 64 + m * 32 + l31;
        const int bbk = (brow * 128 + ks * 32 + kh16) ^ ((brow & 7) << 4);
        fbh[m] = *(const bf16x8*)((const char*)sBh + bbk);
        fbl[m] = *(const bf16x8*)((const char*)sBl + bbk);
      }
#pragma unroll
      for (int m = 0; m < 2; ++m)
#pragma unroll
        for (int n = 0; n < 2; ++n) {
          acc[m][n] = __builtin_amdgcn_mfma_f32_32x32x16_bf16(fah[m], fbh[n], acc[m][n], 0, 0, 0);
          acc[m][n] = __builtin_amdgcn_mfma_f32_32x32x16_bf16(fah[m], fbl[n], acc[m][n], 0, 0, 0);
        }
    }
    __syncthreads();
  }

  auto apart = [&](int i, int j) -> float {
    const int lo = max(0, max(i, j) - 511);
    const int hi = min(512, min(i, j));
    if (lo > hi) return 0.f;
    float v = 0.f;
    {
      int o1 = lo + ((0 - lo) & 3), o2 = hi - (hi & 3);
      if (o1 <= o2) { int mx = i - o1, mn = i - o2; v += pa[mx] - (mn >= 4 ? pa[mn - 4] : 0.f); }
    }
    {
      int o1 = lo + ((1 - lo) & 3), o2 = hi - ((hi - 1) & 3);
      if (o1 <= o2) { int mx = j - o1, mn = j - o2; v += pa[mx] - (mn >= 4 ? pa[mn - 4] : 0.f); }
    }
    {
      int o1 = lo + ((2 - lo) & 3), o2 = hi - ((hi - 2) & 3);
      if (o1 <= o2) { int mx = i - o1, mn = i - o2; v += parev[mx] - (mn >= 4 ? parev[mn - 4] : 0.f); }
    }
    {
      int o1 = lo + ((3 - lo) & 3), o2 = hi - ((hi - 3) & 3);
      if (o1 <= o2) { int mx = j - o1, mn = j - o2; v += parev[mx] - (mn >= 4 ? parev[mn - 4] : 0.f); }
    }
    if (i == j) {
      {
        int o1 = lo + ((0 - lo) & 3), o2 = hi - (hi & 3);
        if (o1 <= o2) { int mx = i - o1, mn = i - o2; v += pd[mx] - (mn >= 4 ? pd[mn - 4] : 0.f); }
      }
      {
        int o1 = lo + ((2 - lo) & 3), o2 = hi - ((hi - 2) & 3);
        if (o1 <= o2) { int mx = i - o1, mn = i - o2; v += pdrev[mx] - (mn >= 4 ? pdrev[mn - 4] : 0.f); }
      }
    }
    const int m2 = i + j - 511;
    if (m2 >= 0 && !(m2 & 1)) {
      const int os = m2 >> 1;
      if (os >= lo && os <= hi) {
        const int r = os & 3;
        if (r == 1) v += sdl[j - os];
        else if (r == 3) v += sdl[511 - (j - os)];
      }
    }
    return v;
  };

  const int ocol0 = col0 + wc * 64 + (lane & 31);
  const int rb = (lane >> 5) << 2;
#pragma unroll
  for (int m = 0; m < 2; ++m)
#pragma unroll
    for (int n = 0; n < 2; ++n)
#pragma unroll
      for (int r = 0; r < 16; ++r) {
        const int grow = row0 + wr * 64 + m * 32 + (r & 3) + ((r >> 2) << 3) + rb;
        const int gcol = ocol0 + n * 32;
        const float v = acc[m][n][r] + apart(grow, gcol);
        const size_t off = ((size_t)mat << 21) + ((size_t)grow << 10) + (size_t)gcol;
        const bf16 hb = __float2bfloat16(v);
        Lbase[off] = hb;
        Lbase[off + LM] = __float2bfloat16(v - __bfloat162float(hb));
      }
}

// ---------------------------------------------------------------------------
// batched single-array transpose: D = S^T for one 1024x1024 bf16 array per z.
// ---------------------------------------------------------------------------
struct TPtrs { const bf16* s; bf16* d; };
struct T6 { TPtrs t[6]; };

__global__ __launch_bounds__(256) void transposeB_kernel(T6 p) {
  const bf16* S = p.t[blockIdx.z].s;
  bf16* D = p.t[blockIdx.z].d;
  __shared__ ushort tile[64][68];
  const int i0 = blockIdx.x * 64, j0 = blockIdx.y * 64;
  const int tid = threadIdx.x;
  const int rr = tid >> 4;
  const int cc = (tid & 15) * 4;
#pragma unroll
  for (int it = 0; it < 4; ++it) {
    const int row = it * 16 + rr;
    const size_t so = (size_t)(i0 + row) * 1024 + j0 + cc;
    ushort4 v = *(const ushort4*)((const ushort*)S + so);
    tile[row][cc] = v.x; tile[row][cc + 1] = v.y;
    tile[row][cc + 2] = v.z; tile[row][cc + 3] = v.w;
  }
  __syncthreads();
#pragma unroll
  for (int it = 0; it < 4; ++it) {
    const int row = it * 16 + rr;
    ushort4 o;
    o.x = tile[cc][row];     o.y = tile[cc + 1][row];
    o.z = tile[cc + 2][row]; o.w = tile[cc + 3][row];
    const size_t dofs = (size_t)(j0 + row) * 1024 + i0 + cc;
    *(ushort4*)((ushort*)D + dofs) = o;
  }
}

// ---------------------------------------------------------------------------
// batched 2-pass chain GEMM v2 (R16/R17-validated ring-3 counted-wait):
// Y = A * B^T per z.  A single-bf16; B pair (lo at b+LM).  Output split.
// 64x64 tile, 4 waves, BK=64, ring of 3 LDS buffers; stage T+2 during T;
// one barrier per tile; vmcnt(6) (never 0 until tail).
// ---------------------------------------------------------------------------
struct GPtrs { const bf16* a; const bf16* b; bf16* yh; bf16* yl; };
struct G4 { GPtrs g[4]; };

__global__ __launch_bounds__(256) void chaingemm4_kernel(G4 p) {
  GPtrs q = p.g[blockIdx.z];
  const bf16* A = q.a;
  const bf16* Bh = q.b;
  const bf16* Bl = q.b + LM;

  __shared__ __align__(16) bf16 smem[3 * 12288];  // 72 KiB (3 ring bufs)

  const int tid = threadIdx.x;
  const int lane = tid & 63;
  const int wave = tid >> 6;
  const int wr = wave >> 1, wc = wave & 1;
  const int r0 = blockIdx.x * 64, c0 = blockIdx.y * 64;

  const int srow = tid >> 3;
  const int scol = (((tid & 7) ^ (srow & 7))) * 8;
  const int dst = tid * 8;
  const size_t ga0 = (size_t)(r0 + srow) * 1024 + scol;
  const size_t gb0 = (size_t)(c0 + srow) * 1024 + scol;

  auto STAGE = [&](int buf, int k0) {
    bf16* base = smem + buf * 12288;
    gload16(base + dst,        A + ga0 + k0);
    gload16(base + 2048 + dst, A + ga0 + 32 * 1024 + k0);
    gload16(base + 4096 + dst,        Bh + gb0 + k0);
    gload16(base + 4096 + 2048 + dst, Bh + gb0 + 32 * 1024 + k0);
    gload16(base + 8192 + dst,        Bl + gb0 + k0);
    gload16(base + 8192 + 2048 + dst, Bl + gb0 + 32 * 1024 + k0);
  };

  const int l31 = lane & 31;
  const int klg = lane >> 5;
  const int ar = wr * 32 + l31;
  const int br = wc * 32 + l31;
  int aoff[4], boff[4];
#pragma unroll
  for (int ks = 0; ks < 4; ++ks) {
    const int lgA = (ks << 1) | klg;
    aoff[ks] = ar * 64 + ((lgA ^ (ar & 7)) << 3);
    boff[ks] = br * 64 + ((lgA ^ (br & 7)) << 3);
  }

  f32x16 acc = {};

  STAGE(0, 0);
  STAGE(1, 64);
  asm volatile("s_waitcnt vmcnt(6)" ::: "memory");
  __builtin_amdgcn_s_barrier();

  for (int t = 0; t < 16; ++t) {
    const int buf = t % 3;
    if (t < 14) STAGE((t + 2) % 3, (t + 2) * 64);

    const bf16* pA = smem + buf * 12288;
    const bf16* pBh = pA + 4096;
    const bf16* pBl = pA + 8192;
#pragma unroll
    for (int ks = 0; ks < 4; ++ks) {
      bf16x8 ah = *(const bf16x8*)(pA + aoff[ks]);
      bf16x8 bh = *(const bf16x8*)(pBh + boff[ks]);
      bf16x8 bl = *(const bf16x8*)(pBl + boff[ks]);
      acc = __builtin_amdgcn_mfma_f32_32x32x16_bf16(ah, bh, acc, 0, 0, 0);
      acc = __builtin_amdgcn_mfma_f32_32x32x16_bf16(ah, bl, acc, 0, 0, 0);
    }
    if (t <= 13) {
      asm volatile("s_waitcnt vmcnt(6)" ::: "memory");
    } else if (t == 14) {
      asm volatile("s_waitcnt vmcnt(0)" ::: "memory");
    }
    __builtin_amdgcn_s_barrier();
  }

  const int oc = c0 + wc * 32 + l31;
  const int rb = (lane >> 5) << 2;
#pragma unroll
  for (int r = 0; r < 16; ++r) {
    const int gr = r0 + wr * 32 + (r & 3) + ((r >> 2) << 3) + rb;
    const size_t off = (size_t)gr * 1024 + oc;
    const float v = acc[r];
    const bf16 hb = __float2bfloat16(v);
    q.yh[off] = hb;
    q.yl[off] = __float2bfloat16(v - __bfloat162float(hb));
  }
}

// ---------------------------------------------------------------------------
// fused SINGLE-PASS big GEMM v4 (R15/R16/R17-validated, unchanged):
//   Y[r][c] = sum_k xh[r][k] * Mcat_h[c][k];  c<1024 -> O0, else O1.
// ---------------------------------------------------------------------------
__global__ __launch_bounds__(256, 2) void gemmbig_kernel(
    const bf16* __restrict__ A, const bf16* __restrict__ Bh_,
    float* __restrict__ Y0, float* __restrict__ Y1) {
  __shared__ __align__(16) bf16 smem[3 * 12288];  // 72 KiB

  const int tid = threadIdx.x;
  const int lane = tid & 63;
  const int wave = tid >> 6;
  const int wr = wave >> 1;
  const int wc = wave & 1;

  const int pdisp = blockIdx.x;
  const int xcd = pdisp & 7;
  const int chk = pdisp >> 3;
  const int row0 = (xcd * 16 + (chk >> 3)) * 128;
  const int col0 = (chk & 7) * 256;

  const int sr = tid >> 2;
  const int sc = ((tid & 3) ^ ((tid >> 3) & 3)) * 8;
  const size_t abase0 = (size_t)(row0 + sr) * NFEAT + sc;
  const size_t abase1 = abase0 + (size_t)64 * NFEAT;
  const size_t bbase = (size_t)(col0 + sr) * NFEAT + sc;
  const int dst = tid * 8;

  auto STAGE_A = [&](int buf, int k0) {
    bf16* base = smem + buf * 12288;
    gload16(base + dst, A + abase0 + k0);
    gload16(base + 2048 + dst, A + abase1 + k0);
  };
  auto STAGE_B = [&](int buf, int k0) {
    bf16* base = smem + buf * 12288 + 4096;
#pragma unroll
    for (int q = 0; q < 4; ++q)
      gload16(base + q * 2048 + dst, Bh_ + bbase + (size_t)(64 * q) * NFEAT + k0);
  };

  const int l15 = lane & 15;
  const int kcol = ((lane >> 4) * 16) ^ (((l15 >> 1) & 3) << 4);
  int aoff[4], boff[8];
#pragma unroll
  for (int fr = 0; fr < 4; ++fr)
    aoff[fr] = (wr * 64 + fr * 16 + l15) * 64 + kcol;
#pragma unroll
  for (int fc = 0; fc < 8; ++fc)
    boff[fc] = 8192 + (wc * 128 + fc * 16 + l15) * 64 + kcol;

  auto LD = [&](int buf, int off) {
    return *(const bf16x8*)((const char*)(smem + buf * 12288) + off);
  };

  f32x4 acc[4][8] = {};

  STAGE_A(0, 0); STAGE_B(0, 0);
  STAGE_A(1, 32); STAGE_B(1, 32);
  asm volatile("s_waitcnt vmcnt(6)" ::: "memory");
  __builtin_amdgcn_s_barrier();

  for (int T = 0; T < 32; ++T) {
    const int buf = T % 3;
    if (T < 30) {
      const int nb = (T + 2) % 3;
      STAGE_A(nb, (T + 2) * 32);
      STAGE_B(nb, (T + 2) * 32);
    }

    bf16x8 fa[4], fb[4];
#pragma unroll
    for (int fr = 0; fr < 4; ++fr) fa[fr] = LD(buf, aoff[fr]);
#pragma unroll
    for (int fc = 0; fc < 4; ++fc) fb[fc] = LD(buf, boff[fc]);
    __builtin_amdgcn_s_setprio(1);
#pragma unroll
    for (int fr = 0; fr < 4; ++fr)
#pragma unroll
      for (int fc = 0; fc < 4; ++fc)
        acc[fr][fc] = __builtin_amdgcn_mfma_f32_16x16x32_bf16(fa[fr], fb[fc], acc[fr][fc], 0, 0, 0);
    __builtin_amdgcn_s_setprio(0);
#pragma unroll
    for (int fc = 0; fc < 4; ++fc) fb[fc] = LD(buf, boff[4 + fc]);
    __builtin_amdgcn_s_setprio(1);
#pragma unroll
    for (int fr = 0; fr < 4; ++fr)
#pragma unroll
      for (int fc = 0; fc < 4; ++fc)
        acc[fr][4 + fc] = __builtin_amdgcn_mfma_f32_16x16x32_bf16(fa[fr], fb[fc], acc[fr][4 + fc], 0, 0, 0);
    __builtin_amdgcn_s_setprio(0);

    if (T <= 29) {
      asm volatile("s_waitcnt vmcnt(6)" ::: "memory");
    } else if (T == 30) {
      asm volatile("s_waitcnt vmcnt(0)" ::: "memory");
    }
    __builtin_amdgcn_s_barrier();
  }

  float* Yb = (col0 < 1024) ? Y0 : (Y1 - 1024);
  const int orow = row0 + wr * 64 + (lane >> 4) * 4;
  const int ocol = col0 + wc * 128 + l15;
#pragma unroll
  for (int fr = 0; fr < 4; ++fr)
#pragma unroll
    for (int fc = 0; fc < 8; ++fc)
#pragma unroll
      for (int r = 0; r < 4; ++r) {
        const int grow = orow + fr * 16 + r;
        const int gcol = ocol + fc * 16;
        Yb[(size_t)grow * NFEAT + (size_t)gcol] = acc[fr][fc][r];
      }
}

// ---------------------------------------------------------------------------
// launch
// ---------------------------------------------------------------------------
extern "C" void kernel_launch(void* const* d_in, const int* in_sizes, int n_in,
                              void* d_out, int out_size, void* d_ws, size_t ws_size,
                              hipStream_t stream) {
  (void)in_sizes; (void)n_in; (void)out_size; (void)ws_size;
  const float* x  = (const float*)d_in[0];
  const float* er = (const float*)d_in[1];
  const float* ed = (const float*)d_in[2];
  const float* dr = (const float*)d_in[3];
  const float* dd = (const float*)d_in[4];

  float* O0 = (float*)d_out;                       // bottleneck (fp32, 64 MB)
  float* O1 = O0 + (size_t)BATCH * NFEAT;          // out (fp32, 64 MB)

  // d_ws: L pairs [16 LM] (32MB) | ab (32KB) | Qh (32MB)
  bf16* Lb = (bf16*)d_ws;
  float* ab = (float*)(Lb + 16 * LM);
  bf16* Qh = (bf16*)(ab + 8 * 1024);

  // O0 scratch: Tpref @0 (64KB); 16 chain slots @1MB.
  float* Tpref = O0;
  bf16* SB = (bf16*)((char*)O0 + (1 << 20));
  auto slot = [&](int s) { return SB + (size_t)s * LM; };

  // O1 scratch (dead until gemmbig): sea-GEMM operands, 3 x 9.44MB.
  const size_t OPN = (size_t)8 * 1024 * KOP;
  bf16* Aoph = (bf16*)O1;
  bf16* Boph = Aoph + OPN;
  bf16* Bopl = Boph + OPN;

  prepfused_kernel<<<8, 256, 0, stream>>>(er, ed, dr, dd, ab, Tpref);
  genops_kernel<<<dim3(1024, 8), 256, 0, stream>>>(er, dr, ab, Aoph, Boph, Bopl, x, Qh);
  buildgemm_kernel<<<dim3(8, 8, 8), 256, 0, stream>>>(Aoph, Boph, Bopl,
                                                      ed, dd, Tpref, Lb);

  // ---- tree fold ----
  {
    T6 p;
    p.t[0] = {Lb + 0 * LM,  slot(0)};   // L1h -> s0  (T1e hi)
    p.t[1] = {Lb + 4 * LM,  slot(2)};   // L3h -> s2  (T2e hi)
    p.t[2] = {Lb + 5 * LM,  slot(3)};   // L3l -> s3  (T2e lo)
    p.t[3] = {Lb + 8 * LM,  slot(4)};   // L5h -> s4  (T1d hi)
    p.t[4] = {Lb + 12 * LM, slot(6)};   // L7h -> s6  (T2d hi)
    p.t[5] = {Lb + 13 * LM, slot(7)};   // L7l -> s7  (T2d lo)
    transposeB_kernel<<<dim3(16, 16, 6), 256, 0, stream>>>(p);
  }
  {
    G4 p;
    p.g[0] = {slot(0),      Lb + 2 * LM,  slot(8),  slot(9)};   // Q1e = T1e * L2^T
    p.g[1] = {Lb + 6 * LM,  slot(2),      slot(10), slot(11)};  // Q2te = L4 * T2e^T
    p.g[2] = {slot(4),      Lb + 10 * LM, slot(12), slot(13)};  // Q1d = T1d * L6^T
    p.g[3] = {Lb + 14 * LM, slot(6),      slot(14), slot(15)};  // Q2td = L8 * T2d^T
    chaingemm4_kernel<<<dim3(16, 16, 4), 256, 0, stream>>>(p);
  }
  {
    G4 p;
    p.g[0] = {slot(8),  slot(10), slot(0), slot(1)};   // Kce = Menc^T
    p.g[1] = {slot(12), slot(14), slot(2), slot(3)};   // Kcd = Mdec^T
    p.g[2] = p.g[0];
    p.g[3] = p.g[1];
    chaingemm4_kernel<<<dim3(16, 16, 2), 256, 0, stream>>>(p);
  }
  {
    T6 p;
    p.t[0] = {slot(0), Lb + 0 * LM};    // Menc -> Mcat rows 0-1023
    p.t[1] = {slot(2), Lb + 2 * LM};    // Mdec
    p.t[2] = p.t[0]; p.t[3] = p.t[0]; p.t[4] = p.t[0]; p.t[5] = p.t[0];
    transposeB_kernel<<<dim3(16, 16, 2), 256, 0, stream>>>(p);
  }
  {
    G4 p;
    p.g[0] = {Lb + 2 * LM, slot(0), Lb + 1 * LM, slot(4)};  // Mtot -> Mcat rows 1024+
    p.g[1] = p.g[0]; p.g[2] = p.g[0]; p.g[3] = p.g[0];
    chaingemm4_kernel<<<dim3(16, 16, 1), 256, 0, stream>>>(p);
  }

  // fused single-pass big GEMM: both outputs from x in one dispatch.
  gemmbig_kernel<<<1024, 256, 0, stream>>>(Qh, Lb, O0, O1);
}